// Round 1
// baseline (2129.533 us; speedup 1.0000x reference)
//
#include <hip/hip_runtime.h>

#define SEQ   1024
#define HD    64
#define NHEAD 16
#define NHB   64
#define QT    32
#define KT    64
#define RB    (QT + KT - 1)   // 95 rows of R needed per (q-tile, k-tile)
#define LP    65              // LDS pad stride in floats (bank-conflict-free)

__global__ __launch_bounds__(256, 2)
void rpsdpa_kernel(const float* __restrict__ Q,
                   const float* __restrict__ Kmat,
                   const float* __restrict__ Vmat,
                   const float* __restrict__ UB,
                   const float* __restrict__ VB,
                   const float* __restrict__ Rmat,
                   float* __restrict__ O)
{
    __shared__ float sK[KT][LP];
    __shared__ float sV[KT][LP];
    __shared__ float sR[RB][LP];
    __shared__ float sQU[QT][LP];
    __shared__ float sQV[QT + 1][LP];

    const int tid  = threadIdx.x;
    const int wv   = tid >> 6;
    const int lane = tid & 63;
    const int b    = blockIdx.y;
    const int h    = b & (NHEAD - 1);      // b = n*H + h  ->  h = b % 16
    const int i0   = blockIdx.x * QT;

    const float* Qb  = Q    + (size_t)b * SEQ * HD;
    const float* Kb  = Kmat + (size_t)b * SEQ * HD;
    const float* Vb  = Vmat + (size_t)b * SEQ * HD;
    const float* Rh  = Rmat + (size_t)h * 2048 * HD;   // R is (H, max_seq_len=2048, K)
    const float* ubh = UB + h * HD;
    const float* vbh = VB + h * HD;

    // Stage q_u (QT rows) and q_v (QT+1 rows): q*K^-0.5 + bias
    for (int idx = tid; idx < QT * (HD / 4); idx += 256) {
        const int r = idx >> 4;
        const int t = (idx & 15) << 2;
        const float4 q4 = *(const float4*)(Qb + (size_t)(i0 + r) * HD + t);
        const float4 u4 = *(const float4*)(ubh + t);
        sQU[r][t + 0] = fmaf(q4.x, 0.125f, u4.x);
        sQU[r][t + 1] = fmaf(q4.y, 0.125f, u4.y);
        sQU[r][t + 2] = fmaf(q4.z, 0.125f, u4.z);
        sQU[r][t + 3] = fmaf(q4.w, 0.125f, u4.w);
    }
    for (int idx = tid; idx < (QT + 1) * (HD / 4); idx += 256) {
        const int r = idx >> 4;
        const int t = (idx & 15) << 2;
        const int i = i0 + r;
        float4 q4 = make_float4(0.f, 0.f, 0.f, 0.f);
        if (i < SEQ) q4 = *(const float4*)(Qb + (size_t)i * HD + t);  // row SEQ never read
        const float4 v4 = *(const float4*)(vbh + t);
        sQV[r][t + 0] = fmaf(q4.x, 0.125f, v4.x);
        sQV[r][t + 1] = fmaf(q4.y, 0.125f, v4.y);
        sQV[r][t + 2] = fmaf(q4.z, 0.125f, v4.z);
        sQV[r][t + 3] = fmaf(q4.w, 0.125f, v4.w);
    }

    // Online-softmax state: wave wv owns rows r = wv*8 + rr
    float m_run[8], s_run[8], acc[8];
#pragma unroll
    for (int rr = 0; rr < 8; ++rr) { m_run[rr] = -3.0e38f; s_run[rr] = 0.f; acc[rr] = 0.f; }

    for (int j0 = 0; j0 < SEQ; j0 += KT) {
        __syncthreads();
        // Stage K, V tiles
        for (int idx = tid; idx < KT * (HD / 4); idx += 256) {
            const int j = idx >> 4;
            const int t = (idx & 15) << 2;
            const float4 k4 = *(const float4*)(Kb + (size_t)(j0 + j) * HD + t);
            sK[j][t + 0] = k4.x; sK[j][t + 1] = k4.y; sK[j][t + 2] = k4.z; sK[j][t + 3] = k4.w;
            const float4 v4 = *(const float4*)(Vb + (size_t)(j0 + j) * HD + t);
            sV[j][t + 0] = v4.x; sV[j][t + 1] = v4.y; sV[j][t + 2] = v4.z; sV[j][t + 3] = v4.w;
        }
        // Stage R band: relative offsets d = j - i span [dlo, dlo+RB-1]
        //   d <= 0  -> R row 1023 + d   (case 1, query row i)
        //   d == 1  -> unused (score pos term is 0)
        //   d >= 2  -> R row d - 2      (case 2, query row i+1)
        const int dlo = j0 - i0 - (QT - 1);
        for (int idx = tid; idx < RB * (HD / 4); idx += 256) {
            const int di = idx >> 4;
            const int t = (idx & 15) << 2;
            const int d = dlo + di;
            const int row = (d <= 0) ? (SEQ - 1 + d) : ((d >= 2) ? (d - 2) : 0);
            const float4 r4 = *(const float4*)(Rh + (size_t)row * HD + t);
            sR[di][t + 0] = r4.x; sR[di][t + 1] = r4.y; sR[di][t + 2] = r4.z; sR[di][t + 3] = r4.w;
        }
        __syncthreads();

#pragma unroll
        for (int rr = 0; rr < 8; ++rr) {
            const int r = wv * 8 + rr;
            const int i = i0 + r;
            const int jrel = i - j0;                  // lane<=jrel: case1; ==jrel+1: zero; else case2
            const int di = lane + (QT - 1) - r;       // always in [0, RB-1]
            const int qvrow = (lane <= jrel) ? r : (r + 1);
            float c = 0.f, p = 0.f;
#pragma unroll 8
            for (int t = 0; t < HD; ++t) {
                c = fmaf(sQU[r][t], sK[lane][t], c);
                p = fmaf(sQV[qvrow][t], sR[di][t], p);
            }
            const float sc = (lane == jrel + 1) ? c : (c + p);

            // wave-wide softmax over this tile's 64 keys
            float mx = sc;
#pragma unroll
            for (int off = 32; off; off >>= 1) mx = fmaxf(mx, __shfl_xor(mx, off));
            const float mn = fmaxf(m_run[rr], mx);
            const float w = __expf(sc - mn);
            float sm = w;
#pragma unroll
            for (int off = 32; off; off >>= 1) sm += __shfl_xor(sm, off);
            const float corr = __expf(m_run[rr] - mn);
            m_run[rr] = mn;
            s_run[rr] = fmaf(s_run[rr], corr, sm);

            // PV: lane = output dim v; broadcast weights via shuffle
            float a = acc[rr] * corr;
#pragma unroll 8
            for (int l = 0; l < KT; ++l)
                a = fmaf(__shfl(w, l), sV[l][lane], a);
            acc[rr] = a;
        }
    }

#pragma unroll
    for (int rr = 0; rr < 8; ++rr) {
        const int i = i0 + wv * 8 + rr;
        O[((size_t)b * SEQ + i) * HD + lane] = acc[rr] / s_run[rr];
    }
}

extern "C" void kernel_launch(void* const* d_in, const int* in_sizes, int n_in,
                              void* d_out, int out_size, void* d_ws, size_t ws_size,
                              hipStream_t stream) {
    const float* Q  = (const float*)d_in[0];
    const float* K  = (const float*)d_in[1];
    const float* V  = (const float*)d_in[2];
    const float* UB = (const float*)d_in[3];
    const float* VB = (const float*)d_in[4];
    const float* R  = (const float*)d_in[5];
    float* O = (float*)d_out;

    dim3 grid(SEQ / QT, NHB);
    rpsdpa_kernel<<<grid, 256, 0, stream>>>(Q, K, V, UB, VB, R, O);
}

// Round 2
// 694.843 us; speedup vs baseline: 3.0648x; 3.0648x over previous
//
#include <hip/hip_runtime.h>

#define SEQ 1024
#define HD  64
#define NHB 64
#define QT  32
#define KT  64
#define NT  16

typedef __attribute__((ext_vector_type(8)))  _Float16 f16x8;
typedef __attribute__((ext_vector_type(4)))  _Float16 f16x4;
typedef __attribute__((ext_vector_type(16))) float    f32x16;

#define MFMA32(a, b, c) __builtin_amdgcn_mfma_f32_32x32x16_f16(a, b, c, 0, 0, 0)

// element index into a linear [rows][64] f16 tile, XOR-swizzled at 16B granularity
__device__ __forceinline__ int sidx(int row, int col) {
    return (row << 6) + (((col << 1) ^ ((row & 7) << 4)) >> 1);
}
// 32x32 MFMA C/D layout: row = (reg&3) + 8*(reg>>2) + 4*(lane>>5)  [m74/m101]
__device__ __forceinline__ int crow(int g, int lane) {
    return (g & 3) + ((g >> 2) << 3) + ((lane >> 5) << 2);
}

__global__ __launch_bounds__(256, 2)
void rpsdpa_mfma(const float* __restrict__ Q, const float* __restrict__ Km,
                 const float* __restrict__ Vm, const float* __restrict__ UB,
                 const float* __restrict__ VB, const float* __restrict__ Rm,
                 float* __restrict__ O)
{
    __shared__ _Float16 __attribute__((aligned(16))) sQU[32 * 64];
    __shared__ _Float16 __attribute__((aligned(16))) sQV[33 * 64];
    __shared__ _Float16 __attribute__((aligned(16))) sK [64 * 64];
    __shared__ _Float16 __attribute__((aligned(16))) sR [96 * 64];
    __shared__ _Float16 __attribute__((aligned(16))) sVt[2][64 * 64];
    __shared__ _Float16 __attribute__((aligned(16))) sW [32 * 64];
    __shared__ float sS[32][68];     // content scores fp32
    __shared__ float sP[33][100];    // pos scores fp32 (band, rows i0..i0+32)
    __shared__ float sCorr[32];
    __shared__ float sSum[32];

    const int tid  = threadIdx.x;
    const int wv   = tid >> 6;
    const int lane = tid & 63;
    const int ar   = lane & 31;
    const int kh   = (lane >> 5) << 3;     // per-lane k-half offset (8 f16)
    const int b    = blockIdx.y;
    const int h    = b & 15;
    const int i0   = blockIdx.x * QT;

    const float* Qb = Q  + (size_t)b * SEQ * HD;
    const float* Kb = Km + (size_t)b * SEQ * HD;
    const float* Vb = Vm + (size_t)b * SEQ * HD;
    const float* Rh = Rm + (size_t)h * 2048 * HD;

    // ---- stage q_u (32 rows), q_v (33 rows) as f16, scaled + biased ----
    for (int u = tid; u < 32 * 16; u += 256) {
        const int r = u >> 4, c = (u & 15) << 2;
        const float4 q4 = *(const float4*)(Qb + (size_t)(i0 + r) * HD + c);
        const float4 u4 = *(const float4*)(UB + h * HD + c);
        f16x4 hv = { (_Float16)fmaf(q4.x, 0.125f, u4.x),
                     (_Float16)fmaf(q4.y, 0.125f, u4.y),
                     (_Float16)fmaf(q4.z, 0.125f, u4.z),
                     (_Float16)fmaf(q4.w, 0.125f, u4.w) };
        *(f16x4*)&sQU[sidx(r, c)] = hv;
    }
    for (int u = tid; u < 33 * 16; u += 256) {
        const int r = u >> 4, c = (u & 15) << 2;
        const int i = i0 + r;
        float4 q4 = make_float4(0.f, 0.f, 0.f, 0.f);
        if (i < SEQ) q4 = *(const float4*)(Qb + (size_t)i * HD + c);
        const float4 v4 = *(const float4*)(VB + h * HD + c);
        f16x4 hv = { (_Float16)fmaf(q4.x, 0.125f, v4.x),
                     (_Float16)fmaf(q4.y, 0.125f, v4.y),
                     (_Float16)fmaf(q4.z, 0.125f, v4.z),
                     (_Float16)fmaf(q4.w, 0.125f, v4.w) };
        *(f16x4*)&sQV[sidx(r, c)] = hv;
    }

    // ---- prologue: global loads for tile 0 (T14 reg-staging) ----
    float4 kreg[4], vreg[4], rreg[6];
    {
        const int dlo = -i0 - 31;
#pragma unroll
        for (int q = 0; q < 4; ++q) {
            const int u = tid + (q << 8);
            const int j = u >> 4, c = (u & 15) << 2;
            kreg[q] = *(const float4*)(Kb + (size_t)j * HD + c);
            vreg[q] = *(const float4*)(Vb + (size_t)j * HD + c);
        }
#pragma unroll
        for (int q = 0; q < 6; ++q) {
            const int u = tid + (q << 8);
            const int di = u >> 4, c = (u & 15) << 2;
            const int d = dlo + di;
            const int row = (d <= 0) ? (SEQ - 1 + d) : ((d >= 2) ? (d - 2) : 0);
            rreg[q] = *(const float4*)(Rh + (size_t)row * HD + c);
        }
    }

    float m_run[8], s_run[8];
#pragma unroll
    for (int rr = 0; rr < 8; ++rr) { m_run[rr] = -3.0e38f; s_run[rr] = 0.f; }
    f32x16 accO0 = {}, accO1 = {};   // PV accumulator (wave 3 only)

    for (int t = 0; t < NT; ++t) {
        const int j0 = t * KT;

        // ---- LDS write tile t (from regs) ----
#pragma unroll
        for (int q = 0; q < 4; ++q) {
            const int u = tid + (q << 8);
            const int j = u >> 4, c = (u & 15) << 2;
            const float4 kv = kreg[q], vv = vreg[q];
            f16x4 k4 = { (_Float16)kv.x, (_Float16)kv.y, (_Float16)kv.z, (_Float16)kv.w };
            *(f16x4*)&sK[sidx(j, c)] = k4;
            _Float16* vt = sVt[t & 1];
            vt[sidx(c + 0, j)] = (_Float16)vv.x;
            vt[sidx(c + 1, j)] = (_Float16)vv.y;
            vt[sidx(c + 2, j)] = (_Float16)vv.z;
            vt[sidx(c + 3, j)] = (_Float16)vv.w;
        }
#pragma unroll
        for (int q = 0; q < 6; ++q) {
            const int u = tid + (q << 8);
            const int di = u >> 4, c = (u & 15) << 2;
            const float4 rv = rreg[q];
            f16x4 r4 = { (_Float16)rv.x, (_Float16)rv.y, (_Float16)rv.z, (_Float16)rv.w };
            *(f16x4*)&sR[sidx(di, c)] = r4;
        }
        // ---- issue global loads for tile t+1 (latency hidden under compute) ----
        if (t + 1 < NT) {
            const int j0n = (t + 1) * KT;
            const int dlo = j0n - i0 - 31;
#pragma unroll
            for (int q = 0; q < 4; ++q) {
                const int u = tid + (q << 8);
                const int j = u >> 4, c = (u & 15) << 2;
                kreg[q] = *(const float4*)(Kb + (size_t)(j0n + j) * HD + c);
                vreg[q] = *(const float4*)(Vb + (size_t)(j0n + j) * HD + c);
            }
#pragma unroll
            for (int q = 0; q < 6; ++q) {
                const int u = tid + (q << 8);
                const int di = u >> 4, c = (u & 15) << 2;
                const int d = dlo + di;
                const int row = (d <= 0) ? (SEQ - 1 + d) : ((d >= 2) ? (d - 2) : 0);
                rreg[q] = *(const float4*)(Rh + (size_t)row * HD + c);
            }
        }
        __syncthreads();

        // ---- MFMA phase: waves 0-2 score tile t; wave 3 does PV of tile t-1 ----
        if (wv == 0) {
            f32x16 a0 = {}, a1 = {};
#pragma unroll
            for (int k0 = 0; k0 < HD; k0 += 16) {
                f16x8 av = *(const f16x8*)&sQU[sidx(ar, k0 + kh)];
                f16x8 b0 = *(const f16x8*)&sK[sidx(ar, k0 + kh)];
                f16x8 b1 = *(const f16x8*)&sK[sidx(32 + ar, k0 + kh)];
                a0 = MFMA32(av, b0, a0);
                a1 = MFMA32(av, b1, a1);
            }
#pragma unroll
            for (int g = 0; g < 16; ++g) {
                const int row = crow(g, lane);
                sS[row][ar]      = a0[g];
                sS[row][32 + ar] = a1[g];
            }
        } else if (wv == 1 || wv == 2) {
            f32x16 p0 = {}, p1 = {}, p2 = {};
            const int arow = (wv == 1) ? ar : 32;   // strip1: broadcast row i0+32
#pragma unroll
            for (int k0 = 0; k0 < HD; k0 += 16) {
                f16x8 av = *(const f16x8*)&sQV[sidx(arow, k0 + kh)];
                f16x8 b0 = *(const f16x8*)&sR[sidx(ar, k0 + kh)];
                f16x8 b1 = *(const f16x8*)&sR[sidx(32 + ar, k0 + kh)];
                f16x8 b2 = *(const f16x8*)&sR[sidx(64 + ar, k0 + kh)];
                p0 = MFMA32(av, b0, p0);
                p1 = MFMA32(av, b1, p1);
                p2 = MFMA32(av, b2, p2);
            }
            if (wv == 1) {
#pragma unroll
                for (int g = 0; g < 16; ++g) {
                    const int row = crow(g, lane);
                    sP[row][ar]      = p0[g];
                    sP[row][32 + ar] = p1[g];
                    sP[row][64 + ar] = p2[g];
                }
            } else if (lane < 32) {      // only global row 32 is needed from strip1
                sP[32][lane]      = p0[0];
                sP[32][32 + lane] = p1[0];
                sP[32][64 + lane] = p2[0];
            }
        } else if (t > 0) {
            const _Float16* vt = sVt[(t - 1) & 1];
#pragma unroll
            for (int g = 0; g < 16; ++g) {
                const float c = sCorr[crow(g, lane)];
                accO0[g] *= c; accO1[g] *= c;
            }
#pragma unroll
            for (int k0 = 0; k0 < KT; k0 += 16) {
                f16x8 aw = *(const f16x8*)&sW[sidx(ar, k0 + kh)];
                f16x8 b0 = *(const f16x8*)&vt[sidx(ar, k0 + kh)];
                f16x8 b1 = *(const f16x8*)&vt[sidx(32 + ar, k0 + kh)];
                accO0 = MFMA32(aw, b0, accO0);
                accO1 = MFMA32(aw, b1, accO1);
            }
        }
        __syncthreads();

        // ---- softmax (all waves, 8 rows each) ----
#pragma unroll
        for (int rr = 0; rr < 8; ++rr) {
            const int r = (wv << 3) + rr;
            const int i = i0 + r;
            const int j = j0 + lane;
            float sc = sS[r][lane];
            if (j != i + 1) sc += sP[(j <= i) ? r : (r + 1)][31 + lane - r];
            float mx = sc;
#pragma unroll
            for (int off = 32; off; off >>= 1) mx = fmaxf(mx, __shfl_xor(mx, off));
            const float mn = fmaxf(m_run[rr], mx);
            const float wt = __expf(sc - mn);
            float sm = wt;
#pragma unroll
            for (int off = 32; off; off >>= 1) sm += __shfl_xor(sm, off);
            const float corr = __expf(m_run[rr] - mn);
            m_run[rr] = mn;
            s_run[rr] = fmaf(s_run[rr], corr, sm);
            sW[sidx(r, lane)] = (_Float16)wt;
            if (lane == 0) {
                sCorr[r] = corr;
                if (t == NT - 1) sSum[r] = s_run[rr];
            }
        }
        __syncthreads();
    }

    // ---- epilogue: PV of last tile + output (wave 3 owns the full 32x64 O tile) ----
    if (wv == 3) {
        const _Float16* vt = sVt[(NT - 1) & 1];
#pragma unroll
        for (int g = 0; g < 16; ++g) {
            const float c = sCorr[crow(g, lane)];
            accO0[g] *= c; accO1[g] *= c;
        }
#pragma unroll
        for (int k0 = 0; k0 < KT; k0 += 16) {
            f16x8 aw = *(const f16x8*)&sW[sidx(ar, k0 + kh)];
            f16x8 b0 = *(const f16x8*)&vt[sidx(ar, k0 + kh)];
            f16x8 b1 = *(const f16x8*)&vt[sidx(32 + ar, k0 + kh)];
            accO0 = MFMA32(aw, b0, accO0);
            accO1 = MFMA32(aw, b1, accO1);
        }
#pragma unroll
        for (int g = 0; g < 16; ++g) {
            const int row = crow(g, lane);
            const float inv = 1.f / sSum[row];
            O[((size_t)b * SEQ + i0 + row) * HD + ar]      = accO0[g] * inv;
            O[((size_t)b * SEQ + i0 + row) * HD + 32 + ar] = accO1[g] * inv;
        }
    }
}

extern "C" void kernel_launch(void* const* d_in, const int* in_sizes, int n_in,
                              void* d_out, int out_size, void* d_ws, size_t ws_size,
                              hipStream_t stream) {
    const float* Q  = (const float*)d_in[0];
    const float* K  = (const float*)d_in[1];
    const float* V  = (const float*)d_in[2];
    const float* UB = (const float*)d_in[3];
    const float* VB = (const float*)d_in[4];
    const float* R  = (const float*)d_in[5];
    float* O = (float*)d_out;

    dim3 grid(SEQ / QT, NHB);
    rpsdpa_mfma<<<grid, 256, 0, stream>>>(Q, K, V, UB, VB, R, O);
}

// Round 4
// 206.282 us; speedup vs baseline: 10.3234x; 3.3684x over previous
//
#include <hip/hip_runtime.h>

#define SEQ   1024
#define HD    64
#define NHB   64
#define QTB   128
#define KT    64
#define NT    16
#define RING  192
#define PST   36

typedef __attribute__((ext_vector_type(8)))  _Float16 f16x8;
typedef __attribute__((ext_vector_type(4)))  _Float16 f16x4;
typedef __attribute__((ext_vector_type(2)))  _Float16 f16x2;
typedef __attribute__((ext_vector_type(16))) float    f32x16;

#define MFMA(a,b,c) __builtin_amdgcn_mfma_f32_32x32x16_f16(a,b,c,0,0,0)

// swizzled element index into a [rows][64] f16 tile (rows are 128B -> XOR byte bits 4..6)
__device__ __forceinline__ int sw(int row, int c) {
    return (row << 6) + (c ^ ((row & 7) << 3));
}
__device__ __forceinline__ float4 ld4(const float* p) { return *(const float4*)p; }
__device__ __forceinline__ f16x8 cvt8(float4 a, float4 b) {
    f16x8 r = { (_Float16)a.x,(_Float16)a.y,(_Float16)a.z,(_Float16)a.w,
                (_Float16)b.x,(_Float16)b.y,(_Float16)b.z,(_Float16)b.w };
    return r;
}
__device__ __forceinline__ void st16(_Float16* base, int row, int c0,
                                     float4 a, float4 b, float4 c, float4 d) {
    *(f16x8*)&base[sw(row, c0)]     = cvt8(a, b);
    *(f16x8*)&base[sw(row, c0 + 8)] = cvt8(c, d);
}
__device__ __forceinline__ void stVp(_Float16* vt, int d, int kp2, float a, float b) {
    *(f16x2*)&vt[(d << 6) + (kp2 ^ ((d & 7) << 3))] = (f16x2){ (_Float16)a, (_Float16)b };
}
__device__ __forceinline__ unsigned pk2(float x, float y) {
    f16x2 h = { (_Float16)x, (_Float16)y };
    return __builtin_bit_cast(unsigned, h);
}
__device__ __forceinline__ f16x8 mk8(unsigned a, unsigned b, unsigned c, unsigned d) {
    union { unsigned u[4]; f16x8 v; } x;
    x.u[0]=a; x.u[1]=b; x.u[2]=c; x.u[3]=d; return x.v;
}
__device__ __forceinline__ f16x8 biasf8(float4 qa, float4 qb, float4 ba, float4 bb) {
    f16x8 r = { (_Float16)fmaf(qa.x,0.125f,ba.x), (_Float16)fmaf(qa.y,0.125f,ba.y),
                (_Float16)fmaf(qa.z,0.125f,ba.z), (_Float16)fmaf(qa.w,0.125f,ba.w),
                (_Float16)fmaf(qb.x,0.125f,bb.x), (_Float16)fmaf(qb.y,0.125f,bb.y),
                (_Float16)fmaf(qb.z,0.125f,bb.z), (_Float16)fmaf(qb.w,0.125f,bb.w) };
    return r;
}

__global__ __launch_bounds__(256, 2)
void rpsdpa3(const float* __restrict__ Q, const float* __restrict__ Km,
             const float* __restrict__ Vm, const float* __restrict__ UB,
             const float* __restrict__ VB, const float* __restrict__ Rm,
             float* __restrict__ O)
{
    __shared__ __attribute__((aligned(16))) _Float16 sK[64*64];
    __shared__ __attribute__((aligned(16))) _Float16 sVt[2][64*64];
    __shared__ __attribute__((aligned(16))) _Float16 sR[RING*64];
    __shared__ __attribute__((aligned(16))) _Float16 sPT[4][96*PST];
    __shared__ __attribute__((aligned(16))) _Float16 sQx[64];

    const int tid  = threadIdx.x;
    const int wv   = tid >> 6;
    const int lane = tid & 63;
    const int ar   = lane & 31;
    const int hi   = lane >> 5;
    const int kh   = hi << 3;
    const int b    = blockIdx.y;
    const int h    = b & 15;
    const int i0   = blockIdx.x * QTB;

    const float* Qb = Q  + (size_t)b * SEQ * HD;
    const float* Kb = Km + (size_t)b * SEQ * HD;
    const float* Vb = Vm + (size_t)b * SEQ * HD;
    const float* Rh = Rm + (size_t)h * 2048 * HD;

    // ---- hoisted QU/QV fragments (this lane's own query row) ----
    f16x8 qu[4], qvf[4];
    {
        const float* qrow = Qb + (size_t)(i0 + 32*wv + ar) * HD;
        const float* ub   = UB + h * HD;
        const float* vb   = VB + h * HD;
#pragma unroll
        for (int ks = 0; ks < 4; ++ks) {
            int c = ks*16 + kh;
            float4 qa = ld4(qrow + c), qb2 = ld4(qrow + c + 4);
            qu[ks]  = biasf8(qa, qb2, ld4(ub + c), ld4(ub + c + 4));
            qvf[ks] = biasf8(qa, qb2, ld4(vb + c), ld4(vb + c + 4));
        }
    }
    // ---- sQx: q_v row i0+128 (for the cross-strip case-2 column of wave 3) ----
    if (tid < 16) {
        int c0 = tid * 4;
        float4 v = make_float4(0.f, 0.f, 0.f, 0.f);
        if (i0 + 128 < SEQ) {
            float4 q4 = ld4(Qb + (size_t)(i0+128)*HD + c0);
            float4 b4 = ld4(VB + h*HD + c0);
            v = make_float4(fmaf(q4.x,0.125f,b4.x), fmaf(q4.y,0.125f,b4.y),
                            fmaf(q4.z,0.125f,b4.z), fmaf(q4.w,0.125f,b4.w));
        }
        f16x4 h4 = { (_Float16)v.x, (_Float16)v.y, (_Float16)v.z, (_Float16)v.w };
        *(f16x4*)&sQx[c0] = h4;
    }
    // ---- prologue staging: R ring (192 rows, tile-0 window), K/V tile 0 ----
#pragma unroll 1
    for (int it = 0; it < 3; ++it) {
        int rr = it*64 + (tid >> 2);
        int d  = -i0 - 127 + rr;
        int row = (d <= 0) ? (1023 + d) : ((d >= 2) ? d - 2 : 0);
        int slot = (d + 1344) % RING;
        int c0 = (tid & 3) * 16;
        const float* s = Rh + (size_t)row*HD + c0;
        st16(sR, slot, c0, ld4(s), ld4(s+4), ld4(s+8), ld4(s+12));
    }
    {
        int r = tid >> 2, c0 = (tid & 3) * 16;
        const float* s = Kb + (size_t)r*HD + c0;
        st16(sK, r, c0, ld4(s), ld4(s+4), ld4(s+8), ld4(s+12));
    }
    {
        int kp2 = (tid & 31) * 2, d0 = (tid >> 5) * 8;
        const float* sA = Vb + (size_t)kp2*HD + d0;
        const float* sB = Vb + (size_t)(kp2+1)*HD + d0;
        float4 a0 = ld4(sA), a1 = ld4(sA+4), b0 = ld4(sB), b1 = ld4(sB+4);
        _Float16* vt = sVt[0];
        stVp(vt, d0+0, kp2, a0.x, b0.x); stVp(vt, d0+1, kp2, a0.y, b0.y);
        stVp(vt, d0+2, kp2, a0.z, b0.z); stVp(vt, d0+3, kp2, a0.w, b0.w);
        stVp(vt, d0+4, kp2, a1.x, b1.x); stVp(vt, d0+5, kp2, a1.y, b1.y);
        stVp(vt, d0+6, kp2, a1.z, b1.z); stVp(vt, d0+7, kp2, a1.w, b1.w);
    }
    __syncthreads();

    float m_run = -3.0e38f, l_run = 0.f, corr = 1.f;
    f32x16 o0 = {}, o1 = {};
    f16x8 wfrag[4];

#pragma unroll 1
    for (int t = 0; t < NT; ++t) {
        const int j0 = t * KT;
        // ================= P2: compute =================
        // prefetch tile t+1 (issued first; consumed after next barrier)
        float4 pk0, pk1, pk2r, pk3, pv0, pv1, pv2, pv3, pr0, pr1, pr2, pr3;
        if (t + 1 < NT) {
            const int j1 = j0 + KT;
            { int r = tid >> 2, c0 = (tid & 3) * 16;
              const float* s = Kb + (size_t)(j1 + r)*HD + c0;
              pk0 = ld4(s); pk1 = ld4(s+4); pk2r = ld4(s+8); pk3 = ld4(s+12); }
            { int kp2 = (tid & 31)*2, d0 = (tid >> 5) * 8;
              const float* sA = Vb + (size_t)(j1 + kp2)*HD + d0;
              const float* sB = Vb + (size_t)(j1 + kp2 + 1)*HD + d0;
              pv0 = ld4(sA); pv1 = ld4(sA+4); pv2 = ld4(sB); pv3 = ld4(sB+4); }
            { int rr = tid >> 2, c0 = (tid & 3) * 16;
              int d = j0 - i0 + 65 + rr;          // new band rows for tile t+1
              int row = (d <= 0) ? (1023 + d) : ((d >= 2) ? d - 2 : 0);
              const float* s = Rh + (size_t)row*HD + c0;
              pr0 = ld4(s); pr1 = ld4(s+4); pr2 = ld4(s+8); pr3 = ld4(s+12); }
        }
        // content: swapped QK^T  (A = K rows -> C[key][query])
        f32x16 c0a = {}, c1a = {};
#pragma unroll
        for (int ks = 0; ks < 4; ++ks) {
            f16x8 a0 = *(const f16x8*)&sK[sw(ar,      ks*16 + kh)];
            f16x8 a1 = *(const f16x8*)&sK[sw(32 + ar, ks*16 + kh)];
            c0a = MFMA(a0, qu[ks], c0a);
            c1a = MFMA(a1, qu[ks], c1a);
        }
        // pos band: A = QV rows (queries), B = R band cols -> C[query][bandpos]
        int sbase = (j0 - i0 - 31 - 32*wv + 1344) % RING;
        int sl0 = sbase + ar;      if (sl0 >= RING) sl0 -= RING;
        int sl1 = sbase + 32 + ar; if (sl1 >= RING) sl1 -= RING;
        int sl2 = sbase + 64 + ar; if (sl2 >= RING) sl2 -= RING;
        f32x16 p0 = {}, p1 = {}, p2 = {};
#pragma unroll
        for (int ks = 0; ks < 4; ++ks) {
            f16x8 b0 = *(const f16x8*)&sR[sw(sl0, ks*16 + kh)];
            f16x8 b1 = *(const f16x8*)&sR[sw(sl1, ks*16 + kh)];
            f16x8 b2 = *(const f16x8*)&sR[sw(sl2, ks*16 + kh)];
            p0 = MFMA(qvf[ks], b0, p0);
            p1 = MFMA(qvf[ks], b1, p1);
            p2 = MFMA(qvf[ks], b2, p2);
        }
        // scatter band to sPT[wv][rl][q]  (f16, b64 quad stores)
#define SCAT(P, CB) { int rl = 32*(CB) + ar; \
    _Float16* dst = &sPT[wv][rl * PST]; \
    { f16x4 h4 = { (_Float16)(P)[0],  (_Float16)(P)[1],  (_Float16)(P)[2],  (_Float16)(P)[3]  }; *(f16x4*)&dst[ 0 + 4*hi] = h4; } \
    { f16x4 h4 = { (_Float16)(P)[4],  (_Float16)(P)[5],  (_Float16)(P)[6],  (_Float16)(P)[7]  }; *(f16x4*)&dst[ 8 + 4*hi] = h4; } \
    { f16x4 h4 = { (_Float16)(P)[8],  (_Float16)(P)[9],  (_Float16)(P)[10], (_Float16)(P)[11] }; *(f16x4*)&dst[16 + 4*hi] = h4; } \
    { f16x4 h4 = { (_Float16)(P)[12], (_Float16)(P)[13], (_Float16)(P)[14], (_Float16)(P)[15] }; *(f16x4*)&dst[24 + 4*hi] = h4; } }
        SCAT(p0, 0) SCAT(p1, 1) SCAT(p2, 2)
#undef SCAT
        // cross-strip column 32: query 32*wv+32
        if (wv > 0 && hi == 0) {
            sPT[wv-1][ar*PST + 32]      = (_Float16)p1[0];
            sPT[wv-1][(32+ar)*PST + 32] = (_Float16)p2[0];
        }
        if (wv == 0) {   // q = i0+128 column for wave 3 (VALU dots)
            int s128 = (j0 - i0 - 127 + 1344) % RING + lane;
            if (s128 >= RING) s128 -= RING;
            float acc = 0.f;
#pragma unroll
            for (int c8 = 0; c8 < 8; ++c8) {
                f16x8 rv = *(const f16x8*)&sR[sw(s128, c8*8)];
                f16x8 qx = *(const f16x8*)&sQx[c8*8];
#pragma unroll
                for (int e = 0; e < 8; ++e) acc = fmaf((float)rv[e], (float)qx[e], acc);
            }
            sPT[3][lane*PST + 32] = (_Float16)acc;
        }
        // PV of tile t-1
        if (t > 0) {
#pragma unroll
            for (int g = 0; g < 16; ++g) {
                int cr = (g & 3) + 8*(g >> 2) + 4*hi;
                float cg = __shfl(corr, cr);
                o0[g] *= cg; o1[g] *= cg;
            }
            const _Float16* vt = sVt[(t-1) & 1];
#pragma unroll
            for (int ks = 0; ks < 4; ++ks) {
                f16x8 b0 = *(const f16x8*)&vt[sw(ar,      ks*16 + kh)];
                f16x8 b1 = *(const f16x8*)&vt[sw(32 + ar, ks*16 + kh)];
                o0 = MFMA(wfrag[ks], b0, o0);
                o1 = MFMA(wfrag[ks], b1, o1);
            }
        }
        __syncthreads();
        // ================= P1: softmax + stage =================
        {
            const int delta = i0 + 32*wv - j0;
            float sarr[32];
#pragma unroll
            for (int g = 0; g < 16; ++g) {
                int cr = (g & 3) + 8*(g >> 2) + 4*hi;
                {
                    int jrel = cr, rl = 31 + jrel - ar;
                    int col = (jrel <= delta + ar) ? ar : ar + 1;
                    float pv = (float)sPT[wv][rl*PST + col];
                    float sc = c0a[g] + pv;
                    if (jrel == delta + ar + 1) sc = c0a[g];
                    sarr[g] = sc;
                }
                {
                    int jrel = cr + 32, rl = 31 + jrel - ar;
                    int col = (jrel <= delta + ar) ? ar : ar + 1;
                    float pv = (float)sPT[wv][rl*PST + col];
                    float sc = c1a[g] + pv;
                    if (jrel == delta + ar + 1) sc = c1a[g];
                    sarr[16 + g] = sc;
                }
            }
            float mx = sarr[0];
#pragma unroll
            for (int i = 1; i < 32; ++i) mx = fmaxf(mx, sarr[i]);
            mx = fmaxf(mx, __shfl_xor(mx, 32));
            float mnew = fmaxf(m_run, mx);
            corr = __expf(m_run - mnew);
            m_run = mnew;
            float ss = 0.f;
#pragma unroll
            for (int i = 0; i < 32; ++i) { sarr[i] = __expf(sarr[i] - mnew); ss += sarr[i]; }
            ss += __shfl_xor(ss, 32);
            l_run = l_run * corr + ss;
            // build PV A-fragments from sarr (in-register redistribution)
#pragma unroll
            for (int ks = 0; ks < 4; ++ks) {
                const int t0 = 2*ks,     G0 = 4*(t0 & 3), A0 = t0 >> 2;
                const int t1 = 2*ks + 1, G1 = 4*(t1 & 3), A1 = t1 >> 2;
                unsigned d00 = pk2(sarr[A0*16+G0+0], sarr[A0*16+G0+1]);
                unsigned d01 = pk2(sarr[A0*16+G0+2], sarr[A0*16+G0+3]);
                unsigned d10 = pk2(sarr[A1*16+G1+0], sarr[A1*16+G1+1]);
                unsigned d11 = pk2(sarr[A1*16+G1+2], sarr[A1*16+G1+3]);
                unsigned own0 = hi ? d10 : d00, own1 = hi ? d11 : d01;
                unsigned oth0 = hi ? d00 : d10, oth1 = hi ? d01 : d11;
                unsigned r0 = (unsigned)__shfl_xor((int)oth0, 32);
                unsigned r1 = (unsigned)__shfl_xor((int)oth1, 32);
                wfrag[ks] = hi ? mk8(r0, r1, own0, own1) : mk8(own0, own1, r0, r1);
            }
            // stage tile t+1 from prefetch regs
            if (t + 1 < NT) {
                { int r = tid >> 2, c0 = (tid & 3) * 16;
                  st16(sK, r, c0, pk0, pk1, pk2r, pk3); }
                { int kp2 = (tid & 31)*2, d0 = (tid >> 5) * 8;
                  _Float16* vt = sVt[(t+1) & 1];
                  stVp(vt, d0+0, kp2, pv0.x, pv2.x); stVp(vt, d0+1, kp2, pv0.y, pv2.y);
                  stVp(vt, d0+2, kp2, pv0.z, pv2.z); stVp(vt, d0+3, kp2, pv0.w, pv2.w);
                  stVp(vt, d0+4, kp2, pv1.x, pv3.x); stVp(vt, d0+5, kp2, pv1.y, pv3.y);
                  stVp(vt, d0+6, kp2, pv1.z, pv3.z); stVp(vt, d0+7, kp2, pv1.w, pv3.w); }
                { int rr = tid >> 2, c0 = (tid & 3) * 16;
                  int d = j0 - i0 + 65 + rr;
                  int slot = (d + 1344) % RING;
                  st16(sR, slot, c0, pr0, pr1, pr2, pr3); }
            }
        }
        __syncthreads();
    }
    // ================= epilogue: PV of last tile + output =================
#pragma unroll
    for (int g = 0; g < 16; ++g) {
        int cr = (g & 3) + 8*(g >> 2) + 4*hi;
        float cg = __shfl(corr, cr);
        o0[g] *= cg; o1[g] *= cg;
    }
    {
        const _Float16* vt = sVt[(NT-1) & 1];
#pragma unroll
        for (int ks = 0; ks < 4; ++ks) {
            f16x8 b0 = *(const f16x8*)&vt[sw(ar,      ks*16 + kh)];
            f16x8 b1 = *(const f16x8*)&vt[sw(32 + ar, ks*16 + kh)];
            o0 = MFMA(wfrag[ks], b0, o0);
            o1 = MFMA(wfrag[ks], b1, o1);
        }
    }
#pragma unroll
    for (int g = 0; g < 16; ++g) {
        int cr = (g & 3) + 8*(g >> 2) + 4*hi;
        float lg = __shfl(l_run, cr);
        float inv = 1.f / lg;
        size_t base = ((size_t)b * SEQ + i0 + 32*wv + cr) * HD;
        O[base + ar]      = o0[g] * inv;
        O[base + 32 + ar] = o1[g] * inv;
    }
}

extern "C" void kernel_launch(void* const* d_in, const int* in_sizes, int n_in,
                              void* d_out, int out_size, void* d_ws, size_t ws_size,
                              hipStream_t stream) {
    const float* Q  = (const float*)d_in[0];
    const float* K  = (const float*)d_in[1];
    const float* V  = (const float*)d_in[2];
    const float* UB = (const float*)d_in[3];
    const float* VB = (const float*)d_in[4];
    const float* R  = (const float*)d_in[5];
    float* O = (float*)d_out;

    dim3 grid(SEQ / QTB, NHB);
    rpsdpa3<<<grid, 256, 0, stream>>>(Q, K, V, UB, VB, R, O);
}

// Round 5
// 144.029 us; speedup vs baseline: 14.7854x; 1.4322x over previous
//
#include <hip/hip_runtime.h>

#define SEQ  1024
#define HD   64
#define QTB  128
#define NT   16
#define RING 192
#define PST  84
#define WSTR (16*PST)    // per-wave strip stride (16 query cols)
#define FB   (8*WSTR)    // fallback column base

typedef __attribute__((ext_vector_type(8))) _Float16 f16x8;
typedef __attribute__((ext_vector_type(4))) _Float16 f16x4;
typedef __attribute__((ext_vector_type(2))) _Float16 f16x2;
typedef __attribute__((ext_vector_type(4))) float    f32x4;

#define MFMA16(a,b,c) __builtin_amdgcn_mfma_f32_16x16x32_f16(a,b,c,0,0,0)

// swizzled element index into a [rows][64] f16 tile (128B rows)
__device__ __forceinline__ int sw(int row, int c) {
    return (row << 6) + (c ^ ((row & 7) << 3));
}
__device__ __forceinline__ float4 ld4(const float* p) { return *(const float4*)p; }
__device__ __forceinline__ f16x8 cvt8(float4 a, float4 b) {
    return (f16x8){(_Float16)a.x,(_Float16)a.y,(_Float16)a.z,(_Float16)a.w,
                   (_Float16)b.x,(_Float16)b.y,(_Float16)b.z,(_Float16)b.w};
}
__device__ __forceinline__ f16x8 biasf8(float4 qa, float4 qb, float4 ba, float4 bb) {
    return (f16x8){(_Float16)fmaf(qa.x,0.125f,ba.x),(_Float16)fmaf(qa.y,0.125f,ba.y),
                   (_Float16)fmaf(qa.z,0.125f,ba.z),(_Float16)fmaf(qa.w,0.125f,ba.w),
                   (_Float16)fmaf(qb.x,0.125f,bb.x),(_Float16)fmaf(qb.y,0.125f,bb.y),
                   (_Float16)fmaf(qb.z,0.125f,bb.z),(_Float16)fmaf(qb.w,0.125f,bb.w)};
}
__device__ __forceinline__ unsigned pk2(float x, float y) {
    f16x2 h = {(_Float16)x, (_Float16)y};
    return __builtin_bit_cast(unsigned, h);
}
__device__ __forceinline__ f16x8 mk8(unsigned a, unsigned b, unsigned c, unsigned d) {
    union { unsigned u[4]; f16x8 v; } x;
    x.u[0]=a; x.u[1]=b; x.u[2]=c; x.u[3]=d; return x.v;
}

__global__ __launch_bounds__(512, 4)
void rpsdpa5(const float* __restrict__ Q, const float* __restrict__ Km,
             const float* __restrict__ Vm, const float* __restrict__ UB,
             const float* __restrict__ VB, const float* __restrict__ Rm,
             float* __restrict__ O)
{
    __shared__ __attribute__((aligned(16))) _Float16 sK[64*64];
    __shared__ __attribute__((aligned(16))) _Float16 sVt[2][64*64];
    __shared__ __attribute__((aligned(16))) _Float16 sR[RING*64];
    __shared__ __attribute__((aligned(16))) _Float16 sPT[FB + PST];
    __shared__ __attribute__((aligned(16))) _Float16 sQx[64];

    const int tid  = threadIdx.x;
    const int wv   = tid >> 6;
    const int lane = tid & 63;
    const int q    = lane & 15;
    const int G    = lane >> 4;

    const int bid = blockIdx.x;
    const int bh  = ((bid & 7) << 3) | ((bid >> 3) & 7);   // XCD swizzle: same bh -> same XCD
    const int i0  = (bid >> 6) * QTB;
    const int h   = bh & 15;

    const float* Qb = Q  + (size_t)bh * SEQ * HD;
    const float* Kb = Km + (size_t)bh * SEQ * HD;
    const float* Vb = Vm + (size_t)bh * SEQ * HD;
    const float* Rh = Rm + (size_t)h * 2048 * HD;

    // ---- qu/qv B-fragments: this lane's query row = i0 + 16*wv + q ----
    f16x8 qu0, qu1, qvf0, qvf1;
    {
        const float* qr = Qb + (size_t)(i0 + 16*wv + q) * HD;
        const float* ub = UB + h * HD;
        const float* vb = VB + h * HD;
        {   int c = 8*G;
            float4 qa = ld4(qr+c), qb2 = ld4(qr+c+4);
            qu0  = biasf8(qa,qb2, ld4(ub+c), ld4(ub+c+4));
            qvf0 = biasf8(qa,qb2, ld4(vb+c), ld4(vb+c+4)); }
        {   int c = 32 + 8*G;
            float4 qa = ld4(qr+c), qb2 = ld4(qr+c+4);
            qu1  = biasf8(qa,qb2, ld4(ub+c), ld4(ub+c+4));
            qvf1 = biasf8(qa,qb2, ld4(vb+c), ld4(vb+c+4)); }
    }
    // ---- sQx: q_v row i0+128 (fallback column source) ----
    if (tid < 16) {
        int c0 = tid * 4;
        float4 v = make_float4(0.f,0.f,0.f,0.f);
        if (i0 + 128 < SEQ) {
            float4 q4 = ld4(Qb + (size_t)(i0+128)*HD + c0);
            float4 b4 = ld4(VB + h*HD + c0);
            v = make_float4(fmaf(q4.x,0.125f,b4.x), fmaf(q4.y,0.125f,b4.y),
                            fmaf(q4.z,0.125f,b4.z), fmaf(q4.w,0.125f,b4.w));
        }
        *(f16x4*)&sQx[c0] = (f16x4){(_Float16)v.x,(_Float16)v.y,(_Float16)v.z,(_Float16)v.w};
    }
    // ---- prologue staging ----
    const int rK  = tid >> 3;            // 0..63
    const int cK  = (tid & 7) * 8;       // 0..56
    const int kp2 = (tid & 31) * 2;      // 0..62 (V key pair)
    const int d0v = (tid >> 5) * 4;      // 0..60 (V dim chunk)
    {
        const float* s = Kb + (size_t)rK*HD + cK;
        *(f16x8*)&sK[sw(rK, cK)] = cvt8(ld4(s), ld4(s+4));
    }
    {
        const float* sA = Vb + (size_t)kp2*HD + d0v;
        float4 a = ld4(sA), b2 = ld4(sA + HD);
        _Float16* vt = sVt[0];
        *(f16x2*)&vt[sw(d0v+0, kp2)] = (f16x2){(_Float16)a.x,(_Float16)b2.x};
        *(f16x2*)&vt[sw(d0v+1, kp2)] = (f16x2){(_Float16)a.y,(_Float16)b2.y};
        *(f16x2*)&vt[sw(d0v+2, kp2)] = (f16x2){(_Float16)a.z,(_Float16)b2.z};
        *(f16x2*)&vt[sw(d0v+3, kp2)] = (f16x2){(_Float16)a.w,(_Float16)b2.w};
    }
#pragma unroll 1
    for (int p = 0; p < 3; ++p) {
        int d = -i0 - 127 + p*64 + rK;
        int row = (d <= 0) ? (1023 + d) : ((d >= 2) ? d - 2 : 0);
        int slot = (d + 1536) % RING;
        const float* s = Rh + (size_t)row*HD + cK;
        *(f16x8*)&sR[sw(slot, cK)] = cvt8(ld4(s), ld4(s+4));
    }
    __syncthreads();

    int sbase = ((-i0 - 16*wv - 15) + 1536) % RING;
    float m_run = -3.0e38f, l_run = 0.f, corr = 0.f;
    f32x4 o0 = {}, o1 = {}, o2 = {}, o3 = {};
    f16x8 wf0 = {}, wf1 = {};

#pragma unroll 1
    for (int t = 0; t < NT; ++t) {
        const int j0 = t * 64;
        // ---- prefetch tile t+1 ----
        float4 fk0, fk1, fv0, fv1, fr0, fr1;
        if (t + 1 < NT) {
            const float* s = Kb + (size_t)(j0 + 64 + rK)*HD + cK;
            fk0 = ld4(s); fk1 = ld4(s+4);
            const float* sA = Vb + (size_t)(j0 + 64 + kp2)*HD + d0v;
            fv0 = ld4(sA); fv1 = ld4(sA + HD);
            int d = j0 - i0 + 65 + rK;
            int row = (d <= 0) ? (1023 + d) : ((d >= 2) ? d - 2 : 0);
            const float* sr = Rh + (size_t)row*HD + cK;
            fr0 = ld4(sr); fr1 = ld4(sr+4);
        }
        __builtin_amdgcn_s_setprio(1);
        // ---- content: C[key][query], A = K rows, B = qu ----
        f32x4 c0 = {}, c1 = {}, c2 = {}, c3 = {};
        {
            int cc = 8*G;
            c0 = MFMA16(*(const f16x8*)&sK[sw( 0+q, cc)], qu0, c0);
            c1 = MFMA16(*(const f16x8*)&sK[sw(16+q, cc)], qu0, c1);
            c2 = MFMA16(*(const f16x8*)&sK[sw(32+q, cc)], qu0, c2);
            c3 = MFMA16(*(const f16x8*)&sK[sw(48+q, cc)], qu0, c3);
            cc = 32 + 8*G;
            c0 = MFMA16(*(const f16x8*)&sK[sw( 0+q, cc)], qu1, c0);
            c1 = MFMA16(*(const f16x8*)&sK[sw(16+q, cc)], qu1, c1);
            c2 = MFMA16(*(const f16x8*)&sK[sw(32+q, cc)], qu1, c2);
            c3 = MFMA16(*(const f16x8*)&sK[sw(48+q, cc)], qu1, c3);
        }
        // ---- pos band: C[bandpos][query], A = R band rows, B = qv ----
        f32x4 p0 = {}, p1 = {}, p2 = {}, p3 = {}, p4 = {};
        {
            int r0 = sbase + q;       if (r0 >= RING) r0 -= RING;
            int r1 = sbase + 16 + q;  if (r1 >= RING) r1 -= RING;
            int r2 = sbase + 32 + q;  if (r2 >= RING) r2 -= RING;
            int r3 = sbase + 48 + q;  if (r3 >= RING) r3 -= RING;
            int r4 = sbase + 64 + q;  if (r4 >= RING) r4 -= RING;
            int cc = 8*G;
            p0 = MFMA16(*(const f16x8*)&sR[sw(r0, cc)], qvf0, p0);
            p1 = MFMA16(*(const f16x8*)&sR[sw(r1, cc)], qvf0, p1);
            p2 = MFMA16(*(const f16x8*)&sR[sw(r2, cc)], qvf0, p2);
            p3 = MFMA16(*(const f16x8*)&sR[sw(r3, cc)], qvf0, p3);
            p4 = MFMA16(*(const f16x8*)&sR[sw(r4, cc)], qvf0, p4);
            cc = 32 + 8*G;
            p0 = MFMA16(*(const f16x8*)&sR[sw(r0, cc)], qvf1, p0);
            p1 = MFMA16(*(const f16x8*)&sR[sw(r1, cc)], qvf1, p1);
            p2 = MFMA16(*(const f16x8*)&sR[sw(r2, cc)], qvf1, p2);
            p3 = MFMA16(*(const f16x8*)&sR[sw(r3, cc)], qvf1, p3);
            p4 = MFMA16(*(const f16x8*)&sR[sw(r4, cc)], qvf1, p4);
        }
        // ---- scatter band (transposed): sPT[wv][query q][bandrow] ----
        {
            _Float16* dst = &sPT[wv*WSTR + q*PST + 4*G];
            *(f16x4*)&dst[ 0] = (f16x4){(_Float16)p0[0],(_Float16)p0[1],(_Float16)p0[2],(_Float16)p0[3]};
            *(f16x4*)&dst[16] = (f16x4){(_Float16)p1[0],(_Float16)p1[1],(_Float16)p1[2],(_Float16)p1[3]};
            *(f16x4*)&dst[32] = (f16x4){(_Float16)p2[0],(_Float16)p2[1],(_Float16)p2[2],(_Float16)p2[3]};
            *(f16x4*)&dst[48] = (f16x4){(_Float16)p3[0],(_Float16)p3[1],(_Float16)p3[2],(_Float16)p3[3]};
            *(f16x4*)&dst[64] = (f16x4){(_Float16)p4[0],(_Float16)p4[1],(_Float16)p4[2],(_Float16)p4[3]};
        }
        // ---- fallback column (query i0+128), wave 7 only: VALU dots ----
        if (wv == 7) {
            int sl = sbase + lane; if (sl >= RING) sl -= RING;
            float acc = 0.f;
#pragma unroll
            for (int c8 = 0; c8 < 8; ++c8) {
                f16x8 rv = *(const f16x8*)&sR[sw(sl, 8*c8)];
                f16x8 qx = *(const f16x8*)&sQx[8*c8];
#pragma unroll
                for (int e = 0; e < 8; ++e) acc = fmaf((float)rv[e], (float)qx[e], acc);
            }
            sPT[FB + 16 + lane] = (_Float16)acc;
        }
        // ---- PV of tile t-1 ----
        if (t > 0) {
            float cg0 = __shfl(corr, 4*G + 0);
            float cg1 = __shfl(corr, 4*G + 1);
            float cg2 = __shfl(corr, 4*G + 2);
            float cg3 = __shfl(corr, 4*G + 3);
            f32x4 cg = {cg0, cg1, cg2, cg3};
            o0 *= cg; o1 *= cg; o2 *= cg; o3 *= cg;
            const _Float16* vt = sVt[(t-1) & 1];
            int cc = 8*G;
            o0 = MFMA16(wf0, *(const f16x8*)&vt[sw( 0+q, cc)], o0);
            o1 = MFMA16(wf0, *(const f16x8*)&vt[sw(16+q, cc)], o1);
            o2 = MFMA16(wf0, *(const f16x8*)&vt[sw(32+q, cc)], o2);
            o3 = MFMA16(wf0, *(const f16x8*)&vt[sw(48+q, cc)], o3);
            cc = 32 + 8*G;
            o0 = MFMA16(wf1, *(const f16x8*)&vt[sw( 0+q, cc)], o0);
            o1 = MFMA16(wf1, *(const f16x8*)&vt[sw(16+q, cc)], o1);
            o2 = MFMA16(wf1, *(const f16x8*)&vt[sw(32+q, cc)], o2);
            o3 = MFMA16(wf1, *(const f16x8*)&vt[sw(48+q, cc)], o3);
        }
        __builtin_amdgcn_s_setprio(0);
        __syncthreads();
        // ================= gather + softmax + wfrag + stage =================
        {
            const int ii = i0 + 16*wv + q - j0;            // i - j0
            const int b1 = wv*WSTR + q*PST + 15 + 4*G - q; // case1 base (col q)
            const int b2 = b1 + PST + ((q == 15) ? 16 : 0);// case2 base (col q+1 / next strip / fallback)
            float sc[16];
#pragma unroll
            for (int t4 = 0; t4 < 4; ++t4) {
#pragma unroll
                for (int r = 0; r < 4; ++r) {
                    const int off = r + 16*t4;
                    const int jrel = 4*G + off;
                    const float v1 = (float)sPT[b1 + off];
                    const float v2 = (float)sPT[b2 + off];
                    const int dj = jrel - ii;
                    const float add = (dj <= 0) ? v1 : ((dj == 1) ? 0.f : v2);
                    const float cv = (t4 == 0) ? c0[r] : (t4 == 1) ? c1[r] : (t4 == 2) ? c2[r] : c3[r];
                    sc[4*t4 + r] = cv + add;
                }
            }
            float mA = fmaxf(fmaxf(fmaxf(sc[0],sc[1]),fmaxf(sc[2],sc[3])),
                             fmaxf(fmaxf(sc[4],sc[5]),fmaxf(sc[6],sc[7])));
            float mB = fmaxf(fmaxf(fmaxf(sc[8],sc[9]),fmaxf(sc[10],sc[11])),
                             fmaxf(fmaxf(sc[12],sc[13]),fmaxf(sc[14],sc[15])));
            float mx = fmaxf(mA, mB);
            mx = fmaxf(mx, __shfl_xor(mx, 16));
            mx = fmaxf(mx, __shfl_xor(mx, 32));
            const float mnew = fmaxf(m_run, mx);
            corr = __expf(m_run - mnew);
            m_run = mnew;
#pragma unroll
            for (int i = 0; i < 16; ++i) sc[i] = __expf(sc[i] - mnew);
            float sA2 = ((sc[0]+sc[1])+(sc[2]+sc[3])) + ((sc[4]+sc[5])+(sc[6]+sc[7]));
            float sB2 = ((sc[8]+sc[9])+(sc[10]+sc[11])) + ((sc[12]+sc[13])+(sc[14]+sc[15]));
            float ssum = sA2 + sB2;
            ssum += __shfl_xor(ssum, 16);
            ssum += __shfl_xor(ssum, 32);
            l_run = l_run * corr + ssum;
            // pack exp'd weights: pkd[2*t4+w]
            unsigned pkd[8];
#pragma unroll
            for (int t4 = 0; t4 < 4; ++t4) {
                pkd[2*t4+0] = pk2(sc[4*t4+0], sc[4*t4+1]);
                pkd[2*t4+1] = pk2(sc[4*t4+2], sc[4*t4+3]);
            }
            const int s0 = q + 32*(G & 1);
            const int s1 = s0 + 16;
            const bool lo = (G < 2);
            {   // kl = 0 : keys 0..31
                unsigned A0 = (unsigned)__shfl((int)pkd[0], s0);
                unsigned A1 = (unsigned)__shfl((int)pkd[1], s0);
                unsigned A2 = (unsigned)__shfl((int)pkd[0], s1);
                unsigned A3 = (unsigned)__shfl((int)pkd[1], s1);
                unsigned B0 = (unsigned)__shfl((int)pkd[2], s0);
                unsigned B1 = (unsigned)__shfl((int)pkd[3], s0);
                unsigned B2 = (unsigned)__shfl((int)pkd[2], s1);
                unsigned B3 = (unsigned)__shfl((int)pkd[3], s1);
                wf0 = mk8(lo?A0:B0, lo?A1:B1, lo?A2:B2, lo?A3:B3);
            }
            {   // kl = 1 : keys 32..63
                unsigned A0 = (unsigned)__shfl((int)pkd[4], s0);
                unsigned A1 = (unsigned)__shfl((int)pkd[5], s0);
                unsigned A2 = (unsigned)__shfl((int)pkd[4], s1);
                unsigned A3 = (unsigned)__shfl((int)pkd[5], s1);
                unsigned B0 = (unsigned)__shfl((int)pkd[6], s0);
                unsigned B1 = (unsigned)__shfl((int)pkd[7], s0);
                unsigned B2 = (unsigned)__shfl((int)pkd[6], s1);
                unsigned B3 = (unsigned)__shfl((int)pkd[7], s1);
                wf1 = mk8(lo?A0:B0, lo?A1:B1, lo?A2:B2, lo?A3:B3);
            }
            // stage tile t+1 from prefetch regs
            if (t + 1 < NT) {
                *(f16x8*)&sK[sw(rK, cK)] = cvt8(fk0, fk1);
                _Float16* vt = sVt[(t+1) & 1];
                *(f16x2*)&vt[sw(d0v+0, kp2)] = (f16x2){(_Float16)fv0.x,(_Float16)fv1.x};
                *(f16x2*)&vt[sw(d0v+1, kp2)] = (f16x2){(_Float16)fv0.y,(_Float16)fv1.y};
                *(f16x2*)&vt[sw(d0v+2, kp2)] = (f16x2){(_Float16)fv0.z,(_Float16)fv1.z};
                *(f16x2*)&vt[sw(d0v+3, kp2)] = (f16x2){(_Float16)fv0.w,(_Float16)fv1.w};
                int d = j0 - i0 + 65 + rK;
                int slot = (d + 1536) % RING;
                *(f16x8*)&sR[sw(slot, cK)] = cvt8(fr0, fr1);
            }
            sbase += 64; if (sbase >= RING) sbase -= RING;
        }
        __syncthreads();
    }
    // ================= epilogue: PV of tile 15 + output =================
    {
        float cg0 = __shfl(corr, 4*G + 0);
        float cg1 = __shfl(corr, 4*G + 1);
        float cg2 = __shfl(corr, 4*G + 2);
        float cg3 = __shfl(corr, 4*G + 3);
        f32x4 cg = {cg0, cg1, cg2, cg3};
        o0 *= cg; o1 *= cg; o2 *= cg; o3 *= cg;
        const _Float16* vt = sVt[(NT-1) & 1];
        int cc = 8*G;
        o0 = MFMA16(wf0, *(const f16x8*)&vt[sw( 0+q, cc)], o0);
        o1 = MFMA16(wf0, *(const f16x8*)&vt[sw(16+q, cc)], o1);
        o2 = MFMA16(wf0, *(const f16x8*)&vt[sw(32+q, cc)], o2);
        o3 = MFMA16(wf0, *(const f16x8*)&vt[sw(48+q, cc)], o3);
        cc = 32 + 8*G;
        o0 = MFMA16(wf1, *(const f16x8*)&vt[sw( 0+q, cc)], o0);
        o1 = MFMA16(wf1, *(const f16x8*)&vt[sw(16+q, cc)], o1);
        o2 = MFMA16(wf1, *(const f16x8*)&vt[sw(32+q, cc)], o2);
        o3 = MFMA16(wf1, *(const f16x8*)&vt[sw(48+q, cc)], o3);
    }
    {
        float i0v = 1.f / __shfl(l_run, 4*G + 0);
        float i1v = 1.f / __shfl(l_run, 4*G + 1);
        float i2v = 1.f / __shfl(l_run, 4*G + 2);
        float i3v = 1.f / __shfl(l_run, 4*G + 3);
        f32x4 inv = {i0v, i1v, i2v, i3v};
#pragma unroll
        for (int reg = 0; reg < 4; ++reg) {
            size_t base = ((size_t)bh*SEQ + i0 + 16*wv + 4*G + reg) * HD + q;
            O[base +  0] = o0[reg] * inv[reg];
            O[base + 16] = o1[reg] * inv[reg];
            O[base + 32] = o2[reg] * inv[reg];
            O[base + 48] = o3[reg] * inv[reg];
        }
    }
}

extern "C" void kernel_launch(void* const* d_in, const int* in_sizes, int n_in,
                              void* d_out, int out_size, void* d_ws, size_t ws_size,
                              hipStream_t stream) {
    const float* Q  = (const float*)d_in[0];
    const float* K  = (const float*)d_in[1];
    const float* V  = (const float*)d_in[2];
    const float* UB = (const float*)d_in[3];
    const float* VB = (const float*)d_in[4];
    const float* R  = (const float*)d_in[5];
    float* O = (float*)d_out;

    rpsdpa5<<<dim3(512), dim3(512), 0, stream>>>(Q, K, V, UB, VB, R, O);
}